// Round 1
// 348.322 us; speedup vs baseline: 1.1551x; 1.1551x over previous
//
#include <hip/hip_runtime.h>
#include <math.h>

#define NUM_USERS 100000
#define NUM_ITEMS 200000
#define N_NODES   300000   // NUM_USERS + NUM_ITEMS
#define EMB       64
#define NUM_INTER 1000000
#define N_EDGES   (2 * NUM_INTER)
#define MAX_SLOTS (N_EDGES + 3 * N_NODES + 16)   // rows padded to multiple of 4
#define BATCH     16384
#define SCAN_BLOCK 1024

#define FILL_BLOCKS ((NUM_INTER + 255) / 256)    // 3907
#define CONV_BLOCKS ((N_NODES * 8 + 255) / 256)  // 9375
#define MARK_BLOCKS ((BATCH * 2) / 256)          // 128
#define PROP_BLOCKS ((N_NODES * 8 + 255) / 256)  // 9375

typedef float    vfloat4 __attribute__((ext_vector_type(4)));
typedef int      vint4   __attribute__((ext_vector_type(4)));
typedef _Float16 half8   __attribute__((ext_vector_type(8)));

// ---------- degree + packed rank (ushort2 in a uint) ----------
__global__ void degree_rank_k(const int* __restrict__ iu, const int* __restrict__ ii,
                              int* __restrict__ deg, unsigned* __restrict__ rr) {
    int e = blockIdx.x * blockDim.x + threadIdx.x;
    if (e < NUM_INTER) {
        int r0 = atomicAdd(&deg[iu[e]], 1);
        int r1 = atomicAdd(&deg[NUM_USERS + ii[e]], 1);
        rr[e] = (unsigned)(r0 | (r1 << 16));   // max degree << 65536
    }
}

// ---------- per-node factors + padded degree + per-block partial sums ----------
__global__ void fact_sum_k(const int* __restrict__ deg, float* __restrict__ dinv,
                           float* __restrict__ d2, float* __restrict__ rcp,
                           int* __restrict__ pdeg, int* __restrict__ bsum) {
    __shared__ int lds[SCAN_BLOCK];
    int g = blockIdx.x * SCAN_BLOCK + threadIdx.x;
    int p = 0;
    if (g < N_NODES) {
        int d = deg[g];
        float fd = (float)d;
        dinv[g] = (d > 0) ? (1.0f / sqrtf(fd)) : 0.0f;
        d2[g]   = (d > 0) ? (1.0f / fd) : 0.0f;
        rcp[g]  = (d > 0) ? sqrtf(fd) : 0.0f;
        p = (d + 3) & ~3;
        pdeg[g] = p;
    }
    lds[threadIdx.x] = p;
    __syncthreads();
    for (int s = SCAN_BLOCK / 2; s > 0; s >>= 1) {
        if (threadIdx.x < s) lds[threadIdx.x] += lds[threadIdx.x + s];
        __syncthreads();
    }
    if (threadIdx.x == 0) bsum[blockIdx.x] = lds[0];
}

// ---------- single-block: scan bsum + softmax(layer_w) + zero fp16 dummy rows ----------
__global__ void mid_k(int* __restrict__ bsum, int nb,
                      const float* __restrict__ lw, float* __restrict__ w,
                      _Float16* __restrict__ semb, _Float16* __restrict__ z1,
                      _Float16* __restrict__ z2) {
    __shared__ int lds[512];
    int t = threadIdx.x;
    int v = (t < nb) ? bsum[t] : 0;
    lds[t] = v;
    __syncthreads();
    for (int ofs = 1; ofs < 512; ofs <<= 1) {
        int x = (t >= ofs) ? lds[t - ofs] : 0;
        __syncthreads();
        lds[t] += x;
        __syncthreads();
    }
    if (t < nb) bsum[t] = lds[t] - v;   // exclusive
    // zero the dummy row (index N_NODES) of each fp16 table: 128 B each
    if (t < 96) {
        unsigned* p = (t < 32) ? (unsigned*)semb : (t < 64) ? (unsigned*)z1 : (unsigned*)z2;
        p[(size_t)N_NODES * 32 + (t & 31)] = 0u;
    }
    if (t == 0) {
        float a = lw[0], b = lw[1], c = lw[2], d = lw[3];
        float m = fmaxf(fmaxf(a, b), fmaxf(c, d));
        float e0 = expf(a - m), e1 = expf(b - m), e2 = expf(c - m), e3 = expf(d - m);
        float s = e0 + e1 + e2 + e3;
        w[0] = e0 / s; w[1] = e1 / s; w[2] = e2 / s; w[3] = e3 / s;
    }
}

__global__ void scan_block_k(const int* __restrict__ v, const int* __restrict__ bsum,
                             int* __restrict__ row_start, int n) {
    __shared__ int lds[SCAN_BLOCK];
    int g = blockIdx.x * SCAN_BLOCK + threadIdx.x;
    int x = (g < n) ? v[g] : 0;
    lds[threadIdx.x] = x;
    __syncthreads();
    for (int ofs = 1; ofs < SCAN_BLOCK; ofs <<= 1) {
        int y = (threadIdx.x >= ofs) ? lds[threadIdx.x - ofs] : 0;
        __syncthreads();
        lds[threadIdx.x] += y;
        __syncthreads();
    }
    if (g < n) row_start[g] = bsum[blockIdx.x] + lds[threadIdx.x] - x;  // exclusive
    if (g == n - 1) row_start[n] = bsum[blockIdx.x] + lds[threadIdx.x]; // inclusive total
}

// ---------- fused: CSR fill (atomic-free) + emb -> fp16 pre-scaled table ----------
// semb[n] = dinv[n] * emb[n]  (unified user|item table, fp16 rows of 128 B)
__global__ void fill_conv_k(const int* __restrict__ iu, const int* __restrict__ ii,
                            const unsigned* __restrict__ rr,
                            const int* __restrict__ row_start, int* __restrict__ nbr,
                            const float* __restrict__ dinv,
                            const float* __restrict__ ue, const float* __restrict__ ie,
                            _Float16* __restrict__ semb) {
    int bid = blockIdx.x;
    if (bid < FILL_BLOCKS) {
        int e = bid * 256 + threadIdx.x;
        if (e < NUM_INTER) {
            int u  = iu[e];
            int it = NUM_USERS + ii[e];
            unsigned r = rr[e];
            nbr[row_start[u]  + (int)(r & 0xffffu)] = it;
            nbr[row_start[it] + (int)(r >> 16)]     = u;
        }
        return;
    }
    int t = (bid - FILL_BLOCKS) * 256 + threadIdx.x;
    int node = t >> 3;
    int q = t & 7;
    if (node >= N_NODES) return;
    const float4* src = (node < NUM_USERS)
        ? (const float4*)ue + (size_t)node * 16
        : (const float4*)ie + (size_t)(node - NUM_USERS) * 16;
    float4 f0 = src[q * 2];
    float4 f1 = src[q * 2 + 1];
    float s = dinv[node];
    half8 h;
    h[0] = (_Float16)(s * f0.x); h[1] = (_Float16)(s * f0.y);
    h[2] = (_Float16)(s * f0.z); h[3] = (_Float16)(s * f0.w);
    h[4] = (_Float16)(s * f1.x); h[5] = (_Float16)(s * f1.y);
    h[6] = (_Float16)(s * f1.z); h[7] = (_Float16)(s * f1.w);
    ((half8*)semb)[(size_t)node * 8 + q] = h;
}

// ---------- fused: mark needed-z2 set + prop layer 1 (pure fp16 sum-gather) ----------
// z1[v] = d2[v] * sum_n semb[n]   ( = dinv[v] * emb1[v] )
__global__ void mark_prop_k(const int* __restrict__ row_start, const int* __restrict__ nbr,
                            const int* __restrict__ deg, const float* __restrict__ d2,
                            const _Float16* __restrict__ semb, _Float16* __restrict__ z1,
                            const int* __restrict__ uid, const int* __restrict__ iid,
                            int* __restrict__ flag) {
    int bid = blockIdx.x;
    if (bid < MARK_BLOCKS) {
        int t = bid * 256 + threadIdx.x;           // < BATCH*2 exactly
        int slot = t >> 1;
        int node = (t & 1) ? (NUM_USERS + iid[slot]) : uid[slot];
        flag[node] = 1;
        int beg = row_start[node];
        int lim = beg + deg[node];
        for (int j = beg; j < lim; ++j) flag[nbr[j]] = 1;
        return;
    }
    int t = (bid - MARK_BLOCKS) * 256 + threadIdx.x;
    int node = t >> 3;
    int q = t & 7;
    if (node >= N_NODES) return;
    int beg = row_start[node], end = row_start[node + 1];
    int lim = beg + deg[node];
    const half8* src = (const half8*)semb;
    float a0 = 0.f, a1 = 0.f, a2 = 0.f, a3 = 0.f, a4 = 0.f, a5 = 0.f, a6 = 0.f, a7 = 0.f;
    for (int j = beg; j < end; j += 8) {
        vint4 na = __builtin_nontemporal_load((const vint4*)(nbr + j));
        vint4 nb = __builtin_nontemporal_load((const vint4*)(nbr + j + 4));
        #pragma unroll
        for (int k = 0; k < 8; ++k) {
            int id = (j + k < lim) ? ((k < 4) ? na[k] : nb[k - 4]) : N_NODES;
            half8 h = src[(size_t)id * 8 + q];
            a0 += (float)h[0]; a1 += (float)h[1]; a2 += (float)h[2]; a3 += (float)h[3];
            a4 += (float)h[4]; a5 += (float)h[5]; a6 += (float)h[6]; a7 += (float)h[7];
        }
    }
    float s = d2[node];
    half8 r;
    r[0] = (_Float16)(s * a0); r[1] = (_Float16)(s * a1);
    r[2] = (_Float16)(s * a2); r[3] = (_Float16)(s * a3);
    r[4] = (_Float16)(s * a4); r[5] = (_Float16)(s * a5);
    r[6] = (_Float16)(s * a6); r[7] = (_Float16)(s * a7);
    __builtin_nontemporal_store(r, (half8*)z1 + (size_t)node * 8 + q);
}

// ---------- prop layer 2 (node-ordered, flag-masked, fp16): z2[v] = d2[v] * sum z1[n] ----------
__global__ void prop_masked_k(const int* __restrict__ row_start, const int* __restrict__ nbr,
                              const int* __restrict__ deg, const float* __restrict__ d2,
                              const int* __restrict__ flag,
                              const _Float16* __restrict__ in, _Float16* __restrict__ out) {
    int t = blockIdx.x * blockDim.x + threadIdx.x;
    int node = t >> 3;
    int q = t & 7;
    if (node >= N_NODES) return;
    if (!flag[node]) return;   // z2 never read at unflagged nodes
    int beg = row_start[node], end = row_start[node + 1];
    int lim = beg + deg[node];
    const half8* src = (const half8*)in;
    float a0 = 0.f, a1 = 0.f, a2 = 0.f, a3 = 0.f, a4 = 0.f, a5 = 0.f, a6 = 0.f, a7 = 0.f;
    for (int j = beg; j < end; j += 8) {
        vint4 na = __builtin_nontemporal_load((const vint4*)(nbr + j));
        vint4 nb = __builtin_nontemporal_load((const vint4*)(nbr + j + 4));
        #pragma unroll
        for (int k = 0; k < 8; ++k) {
            int id = (j + k < lim) ? ((k < 4) ? na[k] : nb[k - 4]) : N_NODES;
            half8 h = src[(size_t)id * 8 + q];
            a0 += (float)h[0]; a1 += (float)h[1]; a2 += (float)h[2]; a3 += (float)h[3];
            a4 += (float)h[4]; a5 += (float)h[5]; a6 += (float)h[6]; a7 += (float)h[7];
        }
    }
    float s = d2[node];
    half8 r;
    r[0] = (_Float16)(s * a0); r[1] = (_Float16)(s * a1);
    r[2] = (_Float16)(s * a2); r[3] = (_Float16)(s * a3);
    r[4] = (_Float16)(s * a4); r[5] = (_Float16)(s * a5);
    r[6] = (_Float16)(s * a6); r[7] = (_Float16)(s * a7);
    __builtin_nontemporal_store(r, (half8*)out + (size_t)node * 8 + q);
}

// ---------- fused epilogue: layer-3 pull at queried nodes + layers 0-2 + dot ----------
// 16 lanes per (u,i) pair: 8 lanes user side, 8 lanes item side, 8 dims/lane
__global__ void fused_score_k(const int* __restrict__ row_start, const int* __restrict__ nbr,
                              const int* __restrict__ deg,
                              const float* __restrict__ dinv, const float* __restrict__ rcp,
                              const float* __restrict__ ue, const float* __restrict__ ie,
                              const _Float16* __restrict__ z1, const _Float16* __restrict__ z2,
                              const int* __restrict__ uid, const int* __restrict__ iid,
                              const float* __restrict__ w4, float* __restrict__ out) {
    int t = blockIdx.x * blockDim.x + threadIdx.x;
    int slot = t >> 4;
    if (slot >= BATCH) return;
    int within = t & 15;
    int side = within >> 3;
    int q = within & 7;

    int node;
    const float4* erow;
    if (side == 0) {
        int u = uid[slot];
        node = u;
        erow = (const float4*)ue + (size_t)u * 16;
    } else {
        int ii_ = iid[slot];
        node = NUM_USERS + ii_;
        erow = (const float4*)ie + (size_t)ii_ * 16;
    }

    float w0 = w4[0], w1 = w4[1], w2 = w4[2], w3 = w4[3];
    int beg = row_start[node], end = row_start[node + 1];
    int lim = beg + deg[node];
    const half8* z2v = (const half8*)z2;

    float a0 = 0.f, a1 = 0.f, a2 = 0.f, a3 = 0.f, a4 = 0.f, a5 = 0.f, a6 = 0.f, a7 = 0.f;
    for (int j = beg; j < end; j += 8) {
        vint4 na = __builtin_nontemporal_load((const vint4*)(nbr + j));
        vint4 nb = __builtin_nontemporal_load((const vint4*)(nbr + j + 4));
        #pragma unroll
        for (int k = 0; k < 8; ++k) {
            int id = (j + k < lim) ? ((k < 4) ? na[k] : nb[k - 4]) : N_NODES;
            half8 h = z2v[(size_t)id * 8 + q];
            a0 += (float)h[0]; a1 += (float)h[1]; a2 += (float)h[2]; a3 += (float)h[3];
            a4 += (float)h[4]; a5 += (float)h[5]; a6 += (float)h[6]; a7 += (float)h[7];
        }
    }

    float r  = rcp[node];
    float di = dinv[node];
    float e[8];
    *reinterpret_cast<float4*>(&e[0]) = erow[q * 2];
    *reinterpret_cast<float4*>(&e[4]) = erow[q * 2 + 1];
    half8 h1 = ((const half8*)z1)[(size_t)node * 8 + q];
    half8 h2 = z2v[(size_t)node * 8 + q];
    float acc[8] = {a0, a1, a2, a3, a4, a5, a6, a7};

    float f[8];
    #pragma unroll
    for (int d = 0; d < 8; ++d)
        f[d] = w0 * e[d] + r * (w1 * (float)h1[d] + w2 * (float)h2[d]) + w3 * di * acc[d];

    float p = 0.f;
    #pragma unroll
    for (int d = 0; d < 8; ++d) {
        float o = __shfl_xor(f[d], 8);   // partner side, same dims
        p += f[d] * o;
    }
    p += __shfl_xor(p, 1);
    p += __shfl_xor(p, 2);
    p += __shfl_xor(p, 4);

    if (within == 0) out[slot] = p;
}

// ---------- launch ----------

extern "C" void kernel_launch(void* const* d_in, const int* in_sizes, int n_in,
                              void* d_out, int out_size, void* d_ws, size_t ws_size,
                              hipStream_t stream) {
    const float* user_emb = (const float*)d_in[0];
    const float* item_emb = (const float*)d_in[1];
    const float* layer_w  = (const float*)d_in[2];
    const int*   inter_u  = (const int*)d_in[3];
    const int*   inter_i  = (const int*)d_in[4];
    const int*   user_ids = (const int*)d_in[5];
    const int*   item_ids = (const int*)d_in[6];
    float* out = (float*)d_out;

    char* base = (char*)d_ws;
    size_t off = 0;
    auto alloc = [&](size_t bytes) -> char* {
        char* p = base + off;
        off = (off + bytes + 255) & ~(size_t)255;
        return p;
    };
    float*    w4        = (float*)    alloc(4 * sizeof(float));
    int*      deg       = (int*)      alloc((size_t)N_NODES * sizeof(int));
    int*      flag      = (int*)      alloc((size_t)N_NODES * sizeof(int));  // adjacent to deg
    int*      pdeg      = (int*)      alloc((size_t)N_NODES * sizeof(int));
    float*    dinv      = (float*)    alloc((size_t)N_NODES * sizeof(float));
    float*    d2        = (float*)    alloc((size_t)N_NODES * sizeof(float));
    float*    rcp       = (float*)    alloc((size_t)N_NODES * sizeof(float));
    int*      row_start = (int*)      alloc(((size_t)N_NODES + 1) * sizeof(int));
    int*      bsum      = (int*)      alloc(512 * sizeof(int));
    unsigned* rr        = (unsigned*) alloc((size_t)NUM_INTER * sizeof(unsigned));
    int*      csr_nbr   = (int*)      alloc((size_t)MAX_SLOTS * sizeof(int));
    _Float16* semb      = (_Float16*) alloc(((size_t)N_NODES + 1) * EMB * sizeof(_Float16));
    _Float16* zA        = (_Float16*) alloc(((size_t)N_NODES + 1) * EMB * sizeof(_Float16));
    _Float16* zB        = (_Float16*) alloc(((size_t)N_NODES + 1) * EMB * sizeof(_Float16));

    const int nscan_blocks = (N_NODES + SCAN_BLOCK - 1) / SCAN_BLOCK;   // 293

    // 1. one memset covers deg + flag (allocated adjacently; pad zeroing harmless)
    size_t span = (size_t)((char*)flag - (char*)deg) + (size_t)N_NODES * sizeof(int);
    hipMemsetAsync(deg, 0, span, stream);

    // 2. degrees + packed ranks
    degree_rank_k<<<(NUM_INTER + 255) / 256, 256, 0, stream>>>(inter_u, inter_i, deg, rr);

    // 3. per-node factors + scan stage 1 (fused)
    fact_sum_k<<<nscan_blocks, SCAN_BLOCK, 0, stream>>>(deg, dinv, d2, rcp, pdeg, bsum);

    // 4. scan stage 2 + softmax + fp16 dummy-row zeroing (single block, fused)
    mid_k<<<1, 512, 0, stream>>>(bsum, nscan_blocks, layer_w, w4, semb, zB, zA);

    // 5. scan stage 3 -> row_start
    scan_block_k<<<nscan_blocks, SCAN_BLOCK, 0, stream>>>(pdeg, bsum, row_start, N_NODES);

    // 6. fused: CSR fill (zero atomics) + dinv-prescaled fp16 emb table
    fill_conv_k<<<FILL_BLOCKS + CONV_BLOCKS, 256, 0, stream>>>(
        inter_u, inter_i, rr, row_start, csr_nbr, dinv, user_emb, item_emb, semb);

    // 7. fused: mark needed-z2 set + layer 1 full (pure fp16 sum-gather): zB = z1
    mark_prop_k<<<MARK_BLOCKS + PROP_BLOCKS, 256, 0, stream>>>(
        row_start, csr_nbr, deg, d2, semb, zB, user_ids, item_ids, flag);

    // 8. layer 2 flag-masked, node-ordered, fp16: zA = z2
    prop_masked_k<<<PROP_BLOCKS, 256, 0, stream>>>(
        row_start, csr_nbr, deg, d2, flag, zB, zA);

    // 9. fused: layer-3 pull at queried nodes + layer 0-2 terms + dot product
    fused_score_k<<<(BATCH * 16 + 255) / 256, 256, 0, stream>>>(
        row_start, csr_nbr, deg, dinv, rcp, user_emb, item_emb,
        zB /*z1*/, zA /*z2*/, user_ids, item_ids, w4, out);
}

// Round 2
// 280.378 us; speedup vs baseline: 1.4350x; 1.2423x over previous
//
#include <hip/hip_runtime.h>
#include <math.h>

#define NUM_USERS 100000
#define NUM_ITEMS 200000
#define N_NODES   300000   // NUM_USERS + NUM_ITEMS
#define EMB       64
#define NUM_INTER 1000000
#define N_EDGES   (2 * NUM_INTER)
#define MAX_SLOTS (N_EDGES + 3 * N_NODES + 16)   // rows padded to multiple of 4
#define BATCH     16384

// ---- bucketed CSR builder geometry ----
#define BSHIFT 9
#define BNODES 512                                  // nodes per bucket
#define NBKT   ((N_NODES + BNODES - 1) / BNODES)    // 586
#define CAP    6144                                 // refs capacity per bucket (max expected ~5400)
#define EDGES_PER_BLOCK 4096                        // 8192 refs per block
#define AB_BLOCKS ((NUM_INTER + EDGES_PER_BLOCK - 1) / EDGES_PER_BLOCK)   // 245

#define CONV_BLOCKS ((N_NODES * 8 + 255) / 256)  // 9375
#define MARK_BLOCKS ((BATCH * 2) / 256)          // 128
#define PROP_BLOCKS ((N_NODES * 8 + 255) / 256)  // 9375

typedef float    vfloat4 __attribute__((ext_vector_type(4)));
typedef int      vint4   __attribute__((ext_vector_type(4)));
typedef _Float16 half8   __attribute__((ext_vector_type(8)));

// ---------- pass AB: scatter (node, partner) refs into bucket regions ----------
// LDS atomics assign block-local ranks; ONE aggregated global atomic per
// (block,bucket) on a 64B-padded cursor replaces 2M far atomics.
__global__ __launch_bounds__(256) void bucket_scatter_k(
        const int* __restrict__ iu, const int* __restrict__ ii,
        int* __restrict__ cursor /*stride 16 ints*/, uint2* __restrict__ pairs) {
    __shared__ int hist[NBKT];
    __shared__ int gbase[NBKT];
    int tid = threadIdx.x;
    for (int b = tid; b < NBKT; b += 256) hist[b] = 0;
    __syncthreads();

    int e0 = blockIdx.x * EDGES_PER_BLOCK;
    int u[16], it[16];
    unsigned pk[32];
    #pragma unroll
    for (int k = 0; k < 16; ++k) {
        int e = e0 + k * 256 + tid;
        bool v = (e < NUM_INTER);
        u[k]  = v ? iu[e] : -1;
        it[k] = v ? (NUM_USERS + ii[e]) : -1;
    }
    #pragma unroll
    for (int k = 0; k < 16; ++k) {
        if (u[k] >= 0) {
            int b0 = u[k] >> BSHIFT;
            int r0 = atomicAdd(&hist[b0], 1);
            pk[2 * k] = ((unsigned)b0 << 13) | (unsigned)r0;    // lrank < 8192
            int b1 = it[k] >> BSHIFT;
            int r1 = atomicAdd(&hist[b1], 1);
            pk[2 * k + 1] = ((unsigned)b1 << 13) | (unsigned)r1;
        }
    }
    __syncthreads();
    for (int b = tid; b < NBKT; b += 256) {
        int c = hist[b];
        if (c) gbase[b] = atomicAdd(&cursor[b * 16], c);
    }
    __syncthreads();
    #pragma unroll
    for (int k = 0; k < 16; ++k) {
        if (u[k] >= 0) {
            unsigned p0 = pk[2 * k];
            int b0 = (int)(p0 >> 13);
            int s0 = gbase[b0] + (int)(p0 & 0x1fffu);
            if (s0 < CAP) pairs[(size_t)b0 * CAP + s0] = make_uint2((unsigned)u[k], (unsigned)it[k]);
            unsigned p1 = pk[2 * k + 1];
            int b1 = (int)(p1 >> 13);
            int s1 = gbase[b1] + (int)(p1 & 0x1fffu);
            if (s1 < CAP) pairs[(size_t)b1 * CAP + s1] = make_uint2((unsigned)it[k], (unsigned)u[k]);
        }
    }
}

// ---------- pass C1: per-bucket degrees (LDS atomics) + factors + padded local offsets ----------
__global__ __launch_bounds__(256) void bucket_deg_k(
        const int* __restrict__ cursor, const uint2* __restrict__ pairs,
        int* __restrict__ deg, float* __restrict__ dinv, float* __restrict__ d2,
        float* __restrict__ rcp, int* __restrict__ lofs, int* __restrict__ bkt_padded) {
    __shared__ int cnt[BNODES];
    __shared__ int sc[256];
    int b = blockIdx.x, tid = threadIdx.x;
    cnt[tid] = 0; cnt[tid + 256] = 0;
    __syncthreads();
    int n = cursor[b * 16]; if (n > CAP) n = CAP;
    const uint2* p = pairs + (size_t)b * CAP;
    for (int j = tid; j < n; j += 256)
        atomicAdd(&cnt[p[j].x & (BNODES - 1)], 1);
    __syncthreads();

    int l0 = 2 * tid, l1 = 2 * tid + 1;
    int c0 = cnt[l0], c1 = cnt[l1];
    int p0 = (c0 + 3) & ~3, p1 = (c1 + 3) & ~3;
    int s = p0 + p1;
    sc[tid] = s;
    __syncthreads();
    for (int o = 1; o < 256; o <<= 1) {
        int x = (tid >= o) ? sc[tid - o] : 0;
        __syncthreads();
        sc[tid] += x;
        __syncthreads();
    }
    int excl = sc[tid] - s;
    int g0 = (b << BSHIFT) + l0;
    int g1 = g0 + 1;
    if (g0 < N_NODES) {
        deg[g0] = c0;
        float fd = (float)c0;
        dinv[g0] = (c0 > 0) ? (1.0f / sqrtf(fd)) : 0.0f;
        d2[g0]   = (c0 > 0) ? (1.0f / fd) : 0.0f;
        rcp[g0]  = (c0 > 0) ? sqrtf(fd) : 0.0f;
        lofs[g0] = excl;
    }
    if (g1 < N_NODES) {
        deg[g1] = c1;
        float fd = (float)c1;
        dinv[g1] = (c1 > 0) ? (1.0f / sqrtf(fd)) : 0.0f;
        d2[g1]   = (c1 > 0) ? (1.0f / fd) : 0.0f;
        rcp[g1]  = (c1 > 0) ? sqrtf(fd) : 0.0f;
        lofs[g1] = excl + p0;
    }
    if (tid == 255) bkt_padded[b] = sc[255];
}

// ---------- pass C2: prefix over bucket totals + softmax + fp16 dummy-row zeroing ----------
__global__ void csr_mid_k(const int* __restrict__ bkt_padded, int* __restrict__ bkt_base,
                          int* __restrict__ row_start,
                          const float* __restrict__ lw, float* __restrict__ w,
                          _Float16* __restrict__ semb, _Float16* __restrict__ z1,
                          _Float16* __restrict__ z2) {
    __shared__ int lds[1024];
    int t = threadIdx.x;
    int v = (t < NBKT) ? bkt_padded[t] : 0;
    lds[t] = v;
    __syncthreads();
    for (int o = 1; o < 1024; o <<= 1) {
        int x = (t >= o) ? lds[t - o] : 0;
        __syncthreads();
        lds[t] += x;
        __syncthreads();
    }
    if (t < NBKT) bkt_base[t] = lds[t] - v;              // exclusive
    if (t == 1023) row_start[N_NODES] = lds[1023];       // grand total (x4-aligned)
    if (t < 96) {
        unsigned* p = (t < 32) ? (unsigned*)semb : (t < 64) ? (unsigned*)z1 : (unsigned*)z2;
        p[(size_t)N_NODES * 32 + (t & 31)] = 0u;
    }
    if (t == 0) {
        float a = lw[0], b = lw[1], c = lw[2], d = lw[3];
        float m = fmaxf(fmaxf(a, b), fmaxf(c, d));
        float e0 = expf(a - m), e1 = expf(b - m), e2 = expf(c - m), e3 = expf(d - m);
        float sm = e0 + e1 + e2 + e3;
        w[0] = e0 / sm; w[1] = e1 / sm; w[2] = e2 / sm; w[3] = e3 / sm;
    }
}

// ---------- pass C3: write row_start + scatter partners into CSR; extra blocks: fp16 conv ----------
// semb[n] = dinv[n] * emb[n]  (unified user|item table, fp16 rows of 128 B)
__global__ __launch_bounds__(256) void bucket_build_k(
        const int* __restrict__ cursor, const uint2* __restrict__ pairs,
        const int* __restrict__ bkt_base, const int* __restrict__ lofs,
        int* __restrict__ row_start, int* __restrict__ nbr,
        const float* __restrict__ dinv,
        const float* __restrict__ ue, const float* __restrict__ ie,
        _Float16* __restrict__ semb) {
    int bid = blockIdx.x;
    int tid = threadIdx.x;
    if (bid >= NBKT) {
        int t = (bid - NBKT) * 256 + tid;
        int node = t >> 3;
        int q = t & 7;
        if (node >= N_NODES) return;
        const float4* src = (node < NUM_USERS)
            ? (const float4*)ue + (size_t)node * 16
            : (const float4*)ie + (size_t)(node - NUM_USERS) * 16;
        float4 f0 = src[q * 2];
        float4 f1 = src[q * 2 + 1];
        float s = dinv[node];
        half8 h;
        h[0] = (_Float16)(s * f0.x); h[1] = (_Float16)(s * f0.y);
        h[2] = (_Float16)(s * f0.z); h[3] = (_Float16)(s * f0.w);
        h[4] = (_Float16)(s * f1.x); h[5] = (_Float16)(s * f1.y);
        h[6] = (_Float16)(s * f1.z); h[7] = (_Float16)(s * f1.w);
        ((half8*)semb)[(size_t)node * 8 + q] = h;
        return;
    }
    __shared__ int ofs[BNODES];
    __shared__ int cnt2[BNODES];
    int b = bid;
    int base = bkt_base[b];
    {
        int g0 = (b << BSHIFT) + tid;
        int g1 = g0 + 256;
        int o0 = (g0 < N_NODES) ? lofs[g0] : 0;
        int o1 = (g1 < N_NODES) ? lofs[g1] : 0;
        ofs[tid] = o0; ofs[tid + 256] = o1;
        cnt2[tid] = 0; cnt2[tid + 256] = 0;
        if (g0 < N_NODES) row_start[g0] = base + o0;
        if (g1 < N_NODES) row_start[g1] = base + o1;
    }
    __syncthreads();
    int n = cursor[b * 16]; if (n > CAP) n = CAP;
    const uint2* p = pairs + (size_t)b * CAP;
    for (int j = tid; j < n; j += 256) {
        uint2 pr = p[j];
        int l = (int)(pr.x & (BNODES - 1));
        int r = atomicAdd(&cnt2[l], 1);
        nbr[base + ofs[l] + r] = (int)pr.y;
    }
}

// ---------- fused: mark needed-z2 set + prop layer 1 (pure fp16 sum-gather) ----------
__global__ void mark_prop_k(const int* __restrict__ row_start, const int* __restrict__ nbr,
                            const int* __restrict__ deg, const float* __restrict__ d2,
                            const _Float16* __restrict__ semb, _Float16* __restrict__ z1,
                            const int* __restrict__ uid, const int* __restrict__ iid,
                            int* __restrict__ flag) {
    int bid = blockIdx.x;
    if (bid < MARK_BLOCKS) {
        int t = bid * 256 + threadIdx.x;           // < BATCH*2 exactly
        int slot = t >> 1;
        int node = (t & 1) ? (NUM_USERS + iid[slot]) : uid[slot];
        flag[node] = 1;
        int beg = row_start[node];
        int lim = beg + deg[node];
        for (int j = beg; j < lim; ++j) flag[nbr[j]] = 1;
        return;
    }
    int t = (bid - MARK_BLOCKS) * 256 + threadIdx.x;
    int node = t >> 3;
    int q = t & 7;
    if (node >= N_NODES) return;
    int beg = row_start[node], end = row_start[node + 1];
    int lim = beg + deg[node];
    const half8* src = (const half8*)semb;
    float a0 = 0.f, a1 = 0.f, a2 = 0.f, a3 = 0.f, a4 = 0.f, a5 = 0.f, a6 = 0.f, a7 = 0.f;
    for (int j = beg; j < end; j += 8) {
        vint4 na = __builtin_nontemporal_load((const vint4*)(nbr + j));
        vint4 nb = __builtin_nontemporal_load((const vint4*)(nbr + j + 4));
        #pragma unroll
        for (int k = 0; k < 8; ++k) {
            int id = (j + k < lim) ? ((k < 4) ? na[k] : nb[k - 4]) : N_NODES;
            half8 h = src[(size_t)id * 8 + q];
            a0 += (float)h[0]; a1 += (float)h[1]; a2 += (float)h[2]; a3 += (float)h[3];
            a4 += (float)h[4]; a5 += (float)h[5]; a6 += (float)h[6]; a7 += (float)h[7];
        }
    }
    float s = d2[node];
    half8 r;
    r[0] = (_Float16)(s * a0); r[1] = (_Float16)(s * a1);
    r[2] = (_Float16)(s * a2); r[3] = (_Float16)(s * a3);
    r[4] = (_Float16)(s * a4); r[5] = (_Float16)(s * a5);
    r[6] = (_Float16)(s * a6); r[7] = (_Float16)(s * a7);
    __builtin_nontemporal_store(r, (half8*)z1 + (size_t)node * 8 + q);
}

// ---------- prop layer 2 (node-ordered, flag-masked, fp16): z2[v] = d2[v] * sum z1[n] ----------
__global__ void prop_masked_k(const int* __restrict__ row_start, const int* __restrict__ nbr,
                              const int* __restrict__ deg, const float* __restrict__ d2,
                              const int* __restrict__ flag,
                              const _Float16* __restrict__ in, _Float16* __restrict__ out) {
    int t = blockIdx.x * blockDim.x + threadIdx.x;
    int node = t >> 3;
    int q = t & 7;
    if (node >= N_NODES) return;
    if (!flag[node]) return;   // z2 never read at unflagged nodes
    int beg = row_start[node], end = row_start[node + 1];
    int lim = beg + deg[node];
    const half8* src = (const half8*)in;
    float a0 = 0.f, a1 = 0.f, a2 = 0.f, a3 = 0.f, a4 = 0.f, a5 = 0.f, a6 = 0.f, a7 = 0.f;
    for (int j = beg; j < end; j += 8) {
        vint4 na = __builtin_nontemporal_load((const vint4*)(nbr + j));
        vint4 nb = __builtin_nontemporal_load((const vint4*)(nbr + j + 4));
        #pragma unroll
        for (int k = 0; k < 8; ++k) {
            int id = (j + k < lim) ? ((k < 4) ? na[k] : nb[k - 4]) : N_NODES;
            half8 h = src[(size_t)id * 8 + q];
            a0 += (float)h[0]; a1 += (float)h[1]; a2 += (float)h[2]; a3 += (float)h[3];
            a4 += (float)h[4]; a5 += (float)h[5]; a6 += (float)h[6]; a7 += (float)h[7];
        }
    }
    float s = d2[node];
    half8 r;
    r[0] = (_Float16)(s * a0); r[1] = (_Float16)(s * a1);
    r[2] = (_Float16)(s * a2); r[3] = (_Float16)(s * a3);
    r[4] = (_Float16)(s * a4); r[5] = (_Float16)(s * a5);
    r[6] = (_Float16)(s * a6); r[7] = (_Float16)(s * a7);
    __builtin_nontemporal_store(r, (half8*)out + (size_t)node * 8 + q);
}

// ---------- fused epilogue: layer-3 pull at queried nodes + layers 0-2 + dot ----------
// 16 lanes per (u,i) pair: 8 lanes user side, 8 lanes item side, 8 dims/lane
__global__ void fused_score_k(const int* __restrict__ row_start, const int* __restrict__ nbr,
                              const int* __restrict__ deg,
                              const float* __restrict__ dinv, const float* __restrict__ rcp,
                              const float* __restrict__ ue, const float* __restrict__ ie,
                              const _Float16* __restrict__ z1, const _Float16* __restrict__ z2,
                              const int* __restrict__ uid, const int* __restrict__ iid,
                              const float* __restrict__ w4, float* __restrict__ out) {
    int t = blockIdx.x * blockDim.x + threadIdx.x;
    int slot = t >> 4;
    if (slot >= BATCH) return;
    int within = t & 15;
    int side = within >> 3;
    int q = within & 7;

    int node;
    const float4* erow;
    if (side == 0) {
        int u = uid[slot];
        node = u;
        erow = (const float4*)ue + (size_t)u * 16;
    } else {
        int ii_ = iid[slot];
        node = NUM_USERS + ii_;
        erow = (const float4*)ie + (size_t)ii_ * 16;
    }

    float w0 = w4[0], w1 = w4[1], w2 = w4[2], w3 = w4[3];
    int beg = row_start[node], end = row_start[node + 1];
    int lim = beg + deg[node];
    const half8* z2v = (const half8*)z2;

    float a0 = 0.f, a1 = 0.f, a2 = 0.f, a3 = 0.f, a4 = 0.f, a5 = 0.f, a6 = 0.f, a7 = 0.f;
    for (int j = beg; j < end; j += 8) {
        vint4 na = __builtin_nontemporal_load((const vint4*)(nbr + j));
        vint4 nb = __builtin_nontemporal_load((const vint4*)(nbr + j + 4));
        #pragma unroll
        for (int k = 0; k < 8; ++k) {
            int id = (j + k < lim) ? ((k < 4) ? na[k] : nb[k - 4]) : N_NODES;
            half8 h = z2v[(size_t)id * 8 + q];
            a0 += (float)h[0]; a1 += (float)h[1]; a2 += (float)h[2]; a3 += (float)h[3];
            a4 += (float)h[4]; a5 += (float)h[5]; a6 += (float)h[6]; a7 += (float)h[7];
        }
    }

    float r  = rcp[node];
    float di = dinv[node];
    float e[8];
    *reinterpret_cast<float4*>(&e[0]) = erow[q * 2];
    *reinterpret_cast<float4*>(&e[4]) = erow[q * 2 + 1];
    half8 h1 = ((const half8*)z1)[(size_t)node * 8 + q];
    half8 h2 = z2v[(size_t)node * 8 + q];
    float acc[8] = {a0, a1, a2, a3, a4, a5, a6, a7};

    float f[8];
    #pragma unroll
    for (int d = 0; d < 8; ++d)
        f[d] = w0 * e[d] + r * (w1 * (float)h1[d] + w2 * (float)h2[d]) + w3 * di * acc[d];

    float p = 0.f;
    #pragma unroll
    for (int d = 0; d < 8; ++d) {
        float o = __shfl_xor(f[d], 8);   // partner side, same dims
        p += f[d] * o;
    }
    p += __shfl_xor(p, 1);
    p += __shfl_xor(p, 2);
    p += __shfl_xor(p, 4);

    if (within == 0) out[slot] = p;
}

// ---------- launch ----------

extern "C" void kernel_launch(void* const* d_in, const int* in_sizes, int n_in,
                              void* d_out, int out_size, void* d_ws, size_t ws_size,
                              hipStream_t stream) {
    const float* user_emb = (const float*)d_in[0];
    const float* item_emb = (const float*)d_in[1];
    const float* layer_w  = (const float*)d_in[2];
    const int*   inter_u  = (const int*)d_in[3];
    const int*   inter_i  = (const int*)d_in[4];
    const int*   user_ids = (const int*)d_in[5];
    const int*   item_ids = (const int*)d_in[6];
    float* out = (float*)d_out;

    char* base = (char*)d_ws;
    size_t off = 0;
    auto alloc = [&](size_t bytes) -> char* {
        char* p = base + off;
        off = (off + bytes + 255) & ~(size_t)255;
        return p;
    };
    float*    w4        = (float*)    alloc(4 * sizeof(float));
    int*      deg       = (int*)      alloc((size_t)N_NODES * sizeof(int));
    float*    dinv      = (float*)    alloc((size_t)N_NODES * sizeof(float));
    float*    d2        = (float*)    alloc((size_t)N_NODES * sizeof(float));
    float*    rcp       = (float*)    alloc((size_t)N_NODES * sizeof(float));
    int*      lofs      = (int*)      alloc((size_t)N_NODES * sizeof(int));
    int*      row_start = (int*)      alloc(((size_t)N_NODES + 1) * sizeof(int));
    int*      bkt_pad   = (int*)      alloc((size_t)NBKT * sizeof(int));
    int*      bkt_base  = (int*)      alloc((size_t)NBKT * sizeof(int));
    int*      flag      = (int*)      alloc((size_t)N_NODES * sizeof(int));   // zeroed (one memset
    int*      cursor    = (int*)      alloc((size_t)NBKT * 16 * sizeof(int)); //  spans flag+cursor)
    uint2*    pairs     = (uint2*)    alloc((size_t)NBKT * CAP * sizeof(uint2));
    int*      csr_nbr   = (int*)      alloc((size_t)MAX_SLOTS * sizeof(int));
    _Float16* semb      = (_Float16*) alloc(((size_t)N_NODES + 1) * EMB * sizeof(_Float16));
    _Float16* zA        = (_Float16*) alloc(((size_t)N_NODES + 1) * EMB * sizeof(_Float16));
    _Float16* zB        = (_Float16*) alloc(((size_t)N_NODES + 1) * EMB * sizeof(_Float16));

    // 1. zero flag + bucket cursors (adjacent allocations, single memset)
    size_t span = (size_t)((char*)cursor - (char*)flag) + (size_t)NBKT * 16 * sizeof(int);
    hipMemsetAsync(flag, 0, span, stream);

    // 2. scatter refs into bucket regions (LDS ranks + ~140K aggregated global atomics)
    bucket_scatter_k<<<AB_BLOCKS, 256, 0, stream>>>(inter_u, inter_i, cursor, pairs);

    // 3. per-bucket degrees + factors + padded local offsets (LDS atomics + LDS scan)
    bucket_deg_k<<<NBKT, 256, 0, stream>>>(cursor, pairs, deg, dinv, d2, rcp, lofs, bkt_pad);

    // 4. prefix over bucket totals + softmax + fp16 dummy-row zeroing
    csr_mid_k<<<1, 1024, 0, stream>>>(bkt_pad, bkt_base, row_start, layer_w, w4, semb, zB, zA);

    // 5. row_start + CSR scatter (LDS ranks); extra blocks: dinv-prescaled fp16 emb table
    bucket_build_k<<<NBKT + CONV_BLOCKS, 256, 0, stream>>>(
        cursor, pairs, bkt_base, lofs, row_start, csr_nbr, dinv, user_emb, item_emb, semb);

    // 6. fused: mark needed-z2 set + layer 1 full (pure fp16 sum-gather): zB = z1
    mark_prop_k<<<MARK_BLOCKS + PROP_BLOCKS, 256, 0, stream>>>(
        row_start, csr_nbr, deg, d2, semb, zB, user_ids, item_ids, flag);

    // 7. layer 2 flag-masked, node-ordered, fp16: zA = z2
    prop_masked_k<<<PROP_BLOCKS, 256, 0, stream>>>(
        row_start, csr_nbr, deg, d2, flag, zB, zA);

    // 8. fused: layer-3 pull at queried nodes + layer 0-2 terms + dot product
    fused_score_k<<<(BATCH * 16 + 255) / 256, 256, 0, stream>>>(
        row_start, csr_nbr, deg, dinv, rcp, user_emb, item_emb,
        zB /*z1*/, zA /*z2*/, user_ids, item_ids, w4, out);
}